// Round 19
// baseline (74.967 us; speedup 1.0000x reference)
//
#include <hip/hip_runtime.h>
#include <stdint.h>

// QuantDenseModelLarge on gfx950 — MFMA formulation.
// Round 19 = round 17/18 resubmission (infra failures, kernel never ran).
// Round 17 = round 12 (41.0 µs best) + TWO row-tiles per wave (256 rows/block).
// Theory (Little's law): x is L3-resident (134MB >> 32MB L2), L3 lat ~500-600cy,
// needed in-flight ~15KB/CU; r12 sustains ~4-8KB -> 3.4 TB/s measured. Two tiles
// per wave double per-iteration loads (4x f32x4, distance-1 rolling buffer) and
// halve per-row weight ds_reads (wf shared by 24 MFMAs). Same occupancy band
// (target VGPR <= 128, 16 waves/CU).
//
// Exact identities:
//   quant weights = qw * sw, qw int in [-7,7]  -> exact in bf16
//   QuantReLU out = qa * s,  qa int in [0,255] -> exact in bf16
//   layers 2/3/out: D = sum(qa*qw) exact in f32; y = D*(s*sw)
//   layer 1: x == hi + lo1 + lo2 EXACTLY (3 bf16 truncation limbs cover 24 bits)
//   rint(max(y,0)) == med3(rint(y), 0, 255) for the clamp (rint monotone)
//
// MFMA layout (hardware-verified via learn_hip m89/m92 ref-checked GEMMs):
//   A (16x32): lane l holds A[m = l&15][k = 8*(l>>4) + j], j=0..7
//   B (32x16): lane l holds B[k = 8*(l>>4) + j][n = l&15]
//   C/D      : lane l, reg r holds D[row = 4*(l>>4) + r][col = l&15]

typedef __attribute__((ext_vector_type(4))) float  f32x4;
typedef __attribute__((ext_vector_type(8))) short  bf16x8;
typedef __attribute__((ext_vector_type(4))) unsigned int u32x4;

namespace {
constexpr int B_  = 131072;
constexpr int IN_ = 256;
constexpr int H_  = 58;
constexpr int C_  = 12;

// ws byte offsets (also the LDS image offsets after staging)
constexpr int W1F = 0;        // [ht4][kt8][lane64][j8] bf16 = 32768 B
constexpr int W2F = 32768;    // [ht4][kt2][lane64][j8] bf16 =  8192 B
constexpr int W3F = 40960;    //                                8192 B
constexpr int WOF = 49152;    // [kt2][lane64][j8]      bf16 =  2048 B
constexpr int PAR = 51200;    // 3*64 {A',b'} f32 | bo[16] | {unused x3, So}
constexpr int WS_STAGE = 52816;  // PAR + 404*4, multiple of 16
constexpr int PITCH = 144;    // bounce-tile row pitch (bytes): 128 data + 16 pad
}

__device__ __forceinline__ uint32_t fu(float f) { return __float_as_uint(f); }
__device__ __forceinline__ float    uf(uint32_t u) { return __uint_as_float(u); }
__device__ __forceinline__ float    truncbf(float v) { return uf(fu(v) & 0xffff0000u); }
// pack bf16(a) into low16, bf16(b) into high16 — single v_perm_b32.
__device__ __forceinline__ uint32_t packbf(float a, float b) {
  return __builtin_amdgcn_perm(fu(b), fu(a), 0x07060302u);
}

__device__ __forceinline__ f32x4 MFMA(u32x4 a, bf16x8 b, f32x4 c) {
  union { u32x4 u; bf16x8 s; } ua; ua.u = a;
  return __builtin_amdgcn_mfma_f32_16x16x32_bf16(ua.s, b, c, 0, 0, 0);
}

// ---------------- prep: quantize + fragment-major arrange + param tables ----------------
__global__ void prep_kernel(
    const float* __restrict__ W1, const float* __restrict__ W2,
    const float* __restrict__ W3, const float* __restrict__ Wo,
    const float* __restrict__ g1, const float* __restrict__ b1, const float* __restrict__ s1,
    const float* __restrict__ g2, const float* __restrict__ b2, const float* __restrict__ s2,
    const float* __restrict__ g3, const float* __restrict__ b3, const float* __restrict__ s3,
    const float* __restrict__ bo,
    uint8_t* __restrict__ wsb)
{
  __shared__ float red[1024];
  const int t = threadIdx.x;
  const int blk = blockIdx.x;
  const float* W; int n;
  switch (blk) {
    case 0: W = W1; n = H_ * IN_; break;
    case 1: W = W2; n = H_ * H_;  break;
    case 2: W = W3; n = H_ * H_;  break;
    default: W = Wo; n = C_ * H_; break;
  }
  float m = 0.f;
  for (int i = t; i < n; i += 1024) m = fmaxf(m, fabsf(W[i]));
  red[t] = m;
  __syncthreads();
  for (int s = 512; s > 0; s >>= 1) { if (t < s) red[t] = fmaxf(red[t], red[t + s]); __syncthreads(); }
  const float sw = red[0] / 7.0f;   // per-tensor symmetric, qmax = 7

  float* pp = (float*)(wsb + PAR);

  if (blk == 0) {
    unsigned short* fr = (unsigned short*)(wsb + W1F);
    for (int i = t; i < 16384; i += 1024) {
      const int j = i & 7, ln = (i >> 3) & 63, kt = (i >> 9) & 7, ht = (i >> 12) & 3;
      const int h = (ht << 4) | (ln & 15);
      const int k = (kt << 5) | (((ln >> 4) & 3) << 3) | j;
      float q = 0.f;
      if (h < H_) q = fminf(fmaxf(rintf(W1[h * IN_ + k] / sw), -7.f), 7.f);
      fr[i] = (unsigned short)(fu(q) >> 16);   // small ints exact in bf16
    }
    const float inv = 1.0f / s1[0];
    if (t < 64) {
      pp[2 * t]     = (t < H_) ? sw * g1[t] * inv : 0.f;   // A' = A/s1
      pp[2 * t + 1] = (t < H_) ? b1[t] * inv : 0.f;        // b' = b/s1
    }
  } else if (blk == 1) {
    unsigned short* fr = (unsigned short*)(wsb + W2F);
    for (int i = t; i < 4096; i += 1024) {
      const int j = i & 7, ln = (i >> 3) & 63, kt = (i >> 9) & 1, ht = (i >> 10) & 3;
      const int h = (ht << 4) | (ln & 15);
      const int k = (kt << 5) | (((ln >> 4) & 3) << 3) | j;
      float q = 0.f;
      if (h < H_ && k < H_) q = fminf(fmaxf(rintf(W2[h * H_ + k] / sw), -7.f), 7.f);
      fr[i] = (unsigned short)(fu(q) >> 16);
    }
    const float inv = 1.0f / s2[0];
    if (t < 64) {
      pp[128 + 2 * t]     = (t < H_) ? s1[0] * sw * g2[t] * inv : 0.f;
      pp[128 + 2 * t + 1] = (t < H_) ? b2[t] * inv : 0.f;
    }
  } else if (blk == 2) {
    unsigned short* fr = (unsigned short*)(wsb + W3F);
    for (int i = t; i < 4096; i += 1024) {
      const int j = i & 7, ln = (i >> 3) & 63, kt = (i >> 9) & 1, ht = (i >> 10) & 3;
      const int h = (ht << 4) | (ln & 15);
      const int k = (kt << 5) | (((ln >> 4) & 3) << 3) | j;
      float q = 0.f;
      if (h < H_ && k < H_) q = fminf(fmaxf(rintf(W3[h * H_ + k] / sw), -7.f), 7.f);
      fr[i] = (unsigned short)(fu(q) >> 16);
    }
    const float inv = 1.0f / s3[0];
    if (t < 64) {
      pp[256 + 2 * t]     = (t < H_) ? s2[0] * sw * g3[t] * inv : 0.f;
      pp[256 + 2 * t + 1] = (t < H_) ? b3[t] * inv : 0.f;
    }
  } else {
    unsigned short* fr = (unsigned short*)(wsb + WOF);
    for (int i = t; i < 1024; i += 1024) {
      const int j = i & 7, ln = (i >> 3) & 63, kt = (i >> 9) & 1;
      const int h = ln & 15;
      const int k = (kt << 5) | (((ln >> 4) & 3) << 3) | j;
      float q = 0.f;
      if (h < C_ && k < H_) q = fminf(fmaxf(rintf(Wo[h * H_ + k] / sw), -7.f), 7.f);
      fr[i] = (unsigned short)(fu(q) >> 16);
    }
    if (t < 16) pp[384 + t] = (t < C_) ? bo[t] : 0.f;
    if (t == 0) pp[403] = s3[0] * sw;   // So
  }
}

// ---------------- epilogue: BN+QuantReLU (prescaled) -> bf16 ints -> LDS bounce -> B-frags ----------------
__device__ __forceinline__ void epilog(
    const f32x4 (&acc)[4], const float* pars, int L,
    uint8_t* bw, int g, int c, bf16x8 (&bfr)[2])
{
  const float* pb = pars + L * 128 + 8 * g;   // {A'(h),b'(h)} pairs, h = 16ht+4g+r
#pragma unroll
  for (int ht = 0; ht < 4; ++ht) {
    float q[4];
#pragma unroll
    for (int r = 0; r < 4; ++r) {
      q[r] = __builtin_amdgcn_fmed3f(
          rintf(fmaf(acc[ht][r], pb[32 * ht + 2 * r], pb[32 * ht + 2 * r + 1])),
          0.f, 255.f);
    }
    uint8_t* bp = bw + c * PITCH + 32 * ht + 8 * g;   // row c, bytes 2h..2h+7
    *(uint32_t*)(bp)     = packbf(q[0], q[1]);
    *(uint32_t*)(bp + 4) = packbf(q[2], q[3]);
  }
  // same-wave cross-lane exchange: DS ops from one wave are processed in order
#pragma unroll
  for (int kt = 0; kt < 2; ++kt) {
    const uint8_t* rp = bw + c * PITCH + 64 * kt + 16 * g;  // k = 32kt+8g+j
    union { u32x4 u; bf16x8 s; } uv;
    uv.u = *(const u32x4*)rp;
    bfr[kt] = uv.s;
  }
}

// ---------------- tail: layers 2/3/out for one row-tile ----------------
__device__ __forceinline__ void tail_path(
    const f32x4 (&acc)[4], const float* pars, const uint8_t* wlds,
    uint8_t* bw, int g, int c, int l, float So, float* out, size_t row)
{
  bf16x8 bfr[2];

  // Layer 2
  epilog(acc, pars, 0, bw, g, c, bfr);
  f32x4 a2[4];
#pragma unroll
  for (int ht = 0; ht < 4; ++ht) a2[ht] = f32x4{0.f, 0.f, 0.f, 0.f};
#pragma unroll
  for (int kt = 0; kt < 2; ++kt) {
#pragma unroll
    for (int ht = 0; ht < 4; ++ht) {
      const u32x4 wf = *(const u32x4*)(wlds + W2F + (size_t)(((ht * 2 + kt) * 64) + l) * 16);
      a2[ht] = MFMA(wf, bfr[kt], a2[ht]);
    }
  }

  // Layer 3
  epilog(a2, pars, 1, bw, g, c, bfr);
  f32x4 a3[4];
#pragma unroll
  for (int ht = 0; ht < 4; ++ht) a3[ht] = f32x4{0.f, 0.f, 0.f, 0.f};
#pragma unroll
  for (int kt = 0; kt < 2; ++kt) {
#pragma unroll
    for (int ht = 0; ht < 4; ++ht) {
      const u32x4 wf = *(const u32x4*)(wlds + W3F + (size_t)(((ht * 2 + kt) * 64) + l) * 16);
      a3[ht] = MFMA(wf, bfr[kt], a3[ht]);
    }
  }

  // Output layer
  epilog(a3, pars, 2, bw, g, c, bfr);
  f32x4 ao = f32x4{0.f, 0.f, 0.f, 0.f};
#pragma unroll
  for (int kt = 0; kt < 2; ++kt) {
    const u32x4 wf = *(const u32x4*)(wlds + WOF + (size_t)((kt * 64) + l) * 16);
    ao = MFMA(wf, bfr[kt], ao);
  }

  const float bo0 = pars[384 + 4 * g + 0];
  const float bo1 = pars[384 + 4 * g + 1];
  const float bo2 = pars[384 + 4 * g + 2];
  const float bo3 = pars[384 + 4 * g + 3];
  f32x4 o;
  o.x = fmaf(ao.x, So, bo0);
  o.y = fmaf(ao.y, So, bo1);
  o.z = fmaf(ao.z, So, bo2);
  o.w = fmaf(ao.w, So, bo3);
  if (g < 3)  // out channels 4g..4g+3; only 0..11 exist
    *(f32x4*)(out + row * C_ + 4 * g) = o;
}

__global__ __launch_bounds__(512, 4) void fused_mfma_kernel(
    const float* __restrict__ x, const uint8_t* __restrict__ wsb,
    float* __restrict__ out)
{
  // Entire ws image (weight fragments + params) staged once per block.
  __shared__ __align__(16) uint8_t wlds[WS_STAGE];
  __shared__ __align__(16) uint8_t bnc[8][16 * PITCH];  // per-wave bounce tiles

  const int t = threadIdx.x;
  const int w = t >> 6, l = t & 63, g = (l >> 4) & 3, c = l & 15;
  const size_t rowbase = (size_t)blockIdx.x * 256;

  // Stage ws -> LDS: 7 chunks of 8KB (512 lanes x 16B), linear both sides.
#pragma unroll
  for (int i = 0; i < 7; ++i) {
    const int off = i * 8192 + t * 16;
    if (off < WS_STAGE) {
      __builtin_amdgcn_global_load_lds(
          (const __attribute__((address_space(1))) void*)(wsb + off),
          (__attribute__((address_space(3))) void*)(wlds + off), 16, 0, 0);
    }
  }

  // Two row-tiles per wave: rows 16w+c and 128+16w+c of this block's 256 rows.
  const float* __restrict__ xrow0 = x + (rowbase + 16 * w + c) * IN_;
  const float* __restrict__ xrow1 = xrow0 + 128 * IN_;

  // Rolling distance-1 double buffer for both tiles: xq[buf][tile][half].
  f32x4 xq[2][2][2];
  xq[0][0][0] = *(const f32x4*)(xrow0 + 8 * g);
  xq[0][0][1] = *(const f32x4*)(xrow0 + 8 * g + 4);
  xq[0][1][0] = *(const f32x4*)(xrow1 + 8 * g);
  xq[0][1][1] = *(const f32x4*)(xrow1 + 8 * g + 4);

  __syncthreads();   // drains vmcnt -> staged image + k-tile 0 (both tiles) ready

  const float* pars = (const float*)(wlds + PAR);
  const float So = pars[403];

  f32x4 acc0[4], acc1[4];
#pragma unroll
  for (int ht = 0; ht < 4; ++ht) {
    acc0[ht] = f32x4{0.f, 0.f, 0.f, 0.f};
    acc1[ht] = f32x4{0.f, 0.f, 0.f, 0.f};
  }

  // ---- Layer 1: 8 k-tiles x 2 row-tiles; wf shared; 4 loads in flight ----
#pragma unroll
  for (int s = 0; s < 8; ++s) {
    const int cb = s & 1, nb = cb ^ 1;   // compile-time under full unroll
    if (s < 7) {
      xq[nb][0][0] = *(const f32x4*)(xrow0 + 32 * (s + 1) + 8 * g);
      xq[nb][0][1] = *(const f32x4*)(xrow0 + 32 * (s + 1) + 8 * g + 4);
      xq[nb][1][0] = *(const f32x4*)(xrow1 + 32 * (s + 1) + 8 * g);
      xq[nb][1][1] = *(const f32x4*)(xrow1 + 32 * (s + 1) + 8 * g + 4);
    }

    u32x4 wf[4];
#pragma unroll
    for (int ht = 0; ht < 4; ++ht)
      wf[ht] = *(const u32x4*)(wlds + W1F + (size_t)(((ht * 8 + s) * 64) + l) * 16);

#pragma unroll
    for (int tile = 0; tile < 2; ++tile) {
      const f32x4 e0 = xq[cb][tile][0];
      const f32x4 e1 = xq[cb][tile][1];
      const float el[8] = {e0.x, e0.y, e0.z, e0.w, e1.x, e1.y, e1.z, e1.w};

      float d[8], e2[8];
#pragma unroll
      for (int q = 0; q < 8; ++q) d[q] = el[q] - truncbf(el[q]);   // exact
#pragma unroll
      for (int q = 0; q < 8; ++q) e2[q] = d[q] - truncbf(d[q]);    // exact

      union { uint32_t u[4]; bf16x8 v; } bh, bl1, bl2;
#pragma unroll
      for (int q = 0; q < 4; ++q) {
        bh.u[q]  = packbf(el[2 * q], el[2 * q + 1]);
        bl1.u[q] = packbf(d[2 * q],  d[2 * q + 1]);
        bl2.u[q] = packbf(e2[2 * q], e2[2 * q + 1]);
      }
      if (tile == 0) {
#pragma unroll
        for (int ht = 0; ht < 4; ++ht) acc0[ht] = MFMA(wf[ht], bh.v,  acc0[ht]);
#pragma unroll
        for (int ht = 0; ht < 4; ++ht) acc0[ht] = MFMA(wf[ht], bl1.v, acc0[ht]);
#pragma unroll
        for (int ht = 0; ht < 4; ++ht) acc0[ht] = MFMA(wf[ht], bl2.v, acc0[ht]);
      } else {
#pragma unroll
        for (int ht = 0; ht < 4; ++ht) acc1[ht] = MFMA(wf[ht], bh.v,  acc1[ht]);
#pragma unroll
        for (int ht = 0; ht < 4; ++ht) acc1[ht] = MFMA(wf[ht], bl1.v, acc1[ht]);
#pragma unroll
        for (int ht = 0; ht < 4; ++ht) acc1[ht] = MFMA(wf[ht], bl2.v, acc1[ht]);
      }
    }
  }

  uint8_t* bw = &bnc[w][0];

  // ---- Tail for tile 0, then tile 1 (bnc reused serially by the same wave) ----
  tail_path(acc0, pars, wlds, bw, g, c, l, So, out, rowbase + 16 * w + c);
  tail_path(acc1, pars, wlds, bw, g, c, l, So, out, rowbase + 128 + 16 * w + c);
}

extern "C" void kernel_launch(void* const* d_in, const int* in_sizes, int n_in,
                              void* d_out, int out_size, void* d_ws, size_t ws_size,
                              hipStream_t stream) {
  // 0:x 1:W1 2:g1 3:b1 4:s1 5:W2 6:g2 7:b2 8:s2 9:W3 10:g3 11:b3 12:s3 13:Wo 14:bo
  const float* x  = (const float*)d_in[0];
  const float* W1 = (const float*)d_in[1];
  const float* g1 = (const float*)d_in[2];
  const float* b1 = (const float*)d_in[3];
  const float* s1 = (const float*)d_in[4];
  const float* W2 = (const float*)d_in[5];
  const float* g2 = (const float*)d_in[6];
  const float* b2 = (const float*)d_in[7];
  const float* s2 = (const float*)d_in[8];
  const float* W3 = (const float*)d_in[9];
  const float* g3 = (const float*)d_in[10];
  const float* b3 = (const float*)d_in[11];
  const float* s3 = (const float*)d_in[12];
  const float* Wo = (const float*)d_in[13];
  const float* bo = (const float*)d_in[14];

  uint8_t* ws = (uint8_t*)d_ws;
  float* out = (float*)d_out;

  prep_kernel<<<4, 1024, 0, stream>>>(W1, W2, W3, Wo, g1, b1, s1, g2, b2, s2,
                                      g3, b3, s3, bo, ws);
  fused_mfma_kernel<<<B_ / 256, 512, 0, stream>>>(x, ws, out);
}

// Round 20
// 41.223 us; speedup vs baseline: 1.8186x; 1.8186x over previous
//
#include <hip/hip_runtime.h>
#include <stdint.h>

// QuantDenseModelLarge on gfx950 — MFMA formulation.
// Round 20 = r12/r15 core + DMA x-staging at FULL occupancy.
// r19's counters (first fused-kernel profile): VGPR=64 (compiler sank my
// register pipelines), MfmaUtil 6%, VALUBusy 9%, Occupancy 43%, and
// FETCH=113MB @ 1.3 TB/s -> x comes from HBM every replay (harness's 512MB
// fills evict L3). HBM lat ~900cy -> need ~22KB/CU in flight; register
// pipelines can't sustain it (compiler minimizes VGPRs). Fix: global_load_lds
// DMA (zero VGPR, can't be sunk) x-staging, 32-float chunks double-buffered,
// vmcnt(2) gates, 16 waves/CU: 16 x 2KB = 32KB/CU in flight.
// LDS: wlds 52.8K + xs 64K + bounce 36.9K = 155.2K <= 160K, 1 block/CU.
//
// Exact identities:
//   quant weights = qw * sw, qw int in [-7,7]  -> exact in bf16
//   QuantReLU out = qa * s,  qa int in [0,255] -> exact in bf16
//   layers 2/3/out: D = sum(qa*qw) exact in f32; y = D*(s*sw)
//   layer 1: x == hi + lo1 + lo2 EXACTLY (3 bf16 truncation limbs cover 24 bits)
//   rint(max(y,0)) == med3(rint(y), 0, 255) for the clamp (rint monotone)
//
// MFMA layout (hardware-verified via learn_hip m89/m92 ref-checked GEMMs):
//   A (16x32): lane l holds A[m = l&15][k = 8*(l>>4) + j], j=0..7
//   B (32x16): lane l holds B[k = 8*(l>>4) + j][n = l&15]
//   C/D      : lane l, reg r holds D[row = 4*(l>>4) + r][col = l&15]
//
// x LDS swizzle (r9-verified, rule #21): DMA dest linear; global source slot
// pre-XOR'd: LDS row r slot s holds global 16B-slot (s ^ (r&7)); read side
// applies the same XOR -> 8 distinct slots across 16 lanes = 2-way bank
// aliasing (free, m136).

typedef __attribute__((ext_vector_type(4))) float  f32x4;
typedef __attribute__((ext_vector_type(8))) short  bf16x8;
typedef __attribute__((ext_vector_type(4))) unsigned int u32x4;

namespace {
constexpr int B_  = 131072;
constexpr int IN_ = 256;
constexpr int H_  = 58;
constexpr int C_  = 12;

// ws byte offsets (also the wlds image offsets after staging)
constexpr int W1F = 0;        // [ht4][kt8][lane64][j8] bf16 = 32768 B
constexpr int W2F = 32768;    // [ht4][kt2][lane64][j8] bf16 =  8192 B
constexpr int W3F = 40960;    //                                8192 B
constexpr int WOF = 49152;    // [kt2][lane64][j8]      bf16 =  2048 B
constexpr int PAR = 51200;    // 3*64 {A',b'} f32 | bo[16] | {unused x3, So}
constexpr int WS_STAGE = 52816;  // PAR + 404*4, multiple of 16
constexpr int PITCH = 144;    // bounce-tile row pitch (bytes): 128 data + 16 pad
}

__device__ __forceinline__ uint32_t fu(float f) { return __float_as_uint(f); }
__device__ __forceinline__ float    uf(uint32_t u) { return __uint_as_float(u); }
__device__ __forceinline__ float    truncbf(float v) { return uf(fu(v) & 0xffff0000u); }
// pack bf16(a) into low16, bf16(b) into high16 — single v_perm_b32.
__device__ __forceinline__ uint32_t packbf(float a, float b) {
  return __builtin_amdgcn_perm(fu(b), fu(a), 0x07060302u);
}

__device__ __forceinline__ f32x4 MFMA(u32x4 a, bf16x8 b, f32x4 c) {
  union { u32x4 u; bf16x8 s; } ua; ua.u = a;
  return __builtin_amdgcn_mfma_f32_16x16x32_bf16(ua.s, b, c, 0, 0, 0);
}

// ---------------- prep: quantize + fragment-major arrange + param tables ----------------
__global__ void prep_kernel(
    const float* __restrict__ W1, const float* __restrict__ W2,
    const float* __restrict__ W3, const float* __restrict__ Wo,
    const float* __restrict__ g1, const float* __restrict__ b1, const float* __restrict__ s1,
    const float* __restrict__ g2, const float* __restrict__ b2, const float* __restrict__ s2,
    const float* __restrict__ g3, const float* __restrict__ b3, const float* __restrict__ s3,
    const float* __restrict__ bo,
    uint8_t* __restrict__ wsb)
{
  __shared__ float red[1024];
  const int t = threadIdx.x;
  const int blk = blockIdx.x;
  const float* W; int n;
  switch (blk) {
    case 0: W = W1; n = H_ * IN_; break;
    case 1: W = W2; n = H_ * H_;  break;
    case 2: W = W3; n = H_ * H_;  break;
    default: W = Wo; n = C_ * H_; break;
  }
  float m = 0.f;
  for (int i = t; i < n; i += 1024) m = fmaxf(m, fabsf(W[i]));
  red[t] = m;
  __syncthreads();
  for (int s = 512; s > 0; s >>= 1) { if (t < s) red[t] = fmaxf(red[t], red[t + s]); __syncthreads(); }
  const float sw = red[0] / 7.0f;   // per-tensor symmetric, qmax = 7

  float* pp = (float*)(wsb + PAR);

  if (blk == 0) {
    unsigned short* fr = (unsigned short*)(wsb + W1F);
    for (int i = t; i < 16384; i += 1024) {
      const int j = i & 7, ln = (i >> 3) & 63, kt = (i >> 9) & 7, ht = (i >> 12) & 3;
      const int h = (ht << 4) | (ln & 15);
      const int k = (kt << 5) | (((ln >> 4) & 3) << 3) | j;
      float q = 0.f;
      if (h < H_) q = fminf(fmaxf(rintf(W1[h * IN_ + k] / sw), -7.f), 7.f);
      fr[i] = (unsigned short)(fu(q) >> 16);   // small ints exact in bf16
    }
    const float inv = 1.0f / s1[0];
    if (t < 64) {
      pp[2 * t]     = (t < H_) ? sw * g1[t] * inv : 0.f;   // A' = A/s1
      pp[2 * t + 1] = (t < H_) ? b1[t] * inv : 0.f;        // b' = b/s1
    }
  } else if (blk == 1) {
    unsigned short* fr = (unsigned short*)(wsb + W2F);
    for (int i = t; i < 4096; i += 1024) {
      const int j = i & 7, ln = (i >> 3) & 63, kt = (i >> 9) & 1, ht = (i >> 10) & 3;
      const int h = (ht << 4) | (ln & 15);
      const int k = (kt << 5) | (((ln >> 4) & 3) << 3) | j;
      float q = 0.f;
      if (h < H_ && k < H_) q = fminf(fmaxf(rintf(W2[h * H_ + k] / sw), -7.f), 7.f);
      fr[i] = (unsigned short)(fu(q) >> 16);
    }
    const float inv = 1.0f / s2[0];
    if (t < 64) {
      pp[128 + 2 * t]     = (t < H_) ? s1[0] * sw * g2[t] * inv : 0.f;
      pp[128 + 2 * t + 1] = (t < H_) ? b2[t] * inv : 0.f;
    }
  } else if (blk == 2) {
    unsigned short* fr = (unsigned short*)(wsb + W3F);
    for (int i = t; i < 4096; i += 1024) {
      const int j = i & 7, ln = (i >> 3) & 63, kt = (i >> 9) & 1, ht = (i >> 10) & 3;
      const int h = (ht << 4) | (ln & 15);
      const int k = (kt << 5) | (((ln >> 4) & 3) << 3) | j;
      float q = 0.f;
      if (h < H_ && k < H_) q = fminf(fmaxf(rintf(W3[h * H_ + k] / sw), -7.f), 7.f);
      fr[i] = (unsigned short)(fu(q) >> 16);
    }
    const float inv = 1.0f / s3[0];
    if (t < 64) {
      pp[256 + 2 * t]     = (t < H_) ? s2[0] * sw * g3[t] * inv : 0.f;
      pp[256 + 2 * t + 1] = (t < H_) ? b3[t] * inv : 0.f;
    }
  } else {
    unsigned short* fr = (unsigned short*)(wsb + WOF);
    for (int i = t; i < 1024; i += 1024) {
      const int j = i & 7, ln = (i >> 3) & 63, kt = (i >> 9) & 1;
      const int h = ln & 15;
      const int k = (kt << 5) | (((ln >> 4) & 3) << 3) | j;
      float q = 0.f;
      if (h < C_ && k < H_) q = fminf(fmaxf(rintf(Wo[h * H_ + k] / sw), -7.f), 7.f);
      fr[i] = (unsigned short)(fu(q) >> 16);
    }
    if (t < 16) pp[384 + t] = (t < C_) ? bo[t] : 0.f;
    if (t == 0) pp[403] = s3[0] * sw;   // So
  }
}

// ---------------- epilogue: BN+QuantReLU (prescaled) -> bf16 ints -> LDS bounce -> B-frags ----------------
__device__ __forceinline__ void epilog(
    const f32x4 (&acc)[4], const float* pars, int L,
    uint8_t* bw, int g, int c, bf16x8 (&bfr)[2])
{
  const float* pb = pars + L * 128 + 8 * g;   // {A'(h),b'(h)} pairs, h = 16ht+4g+r
#pragma unroll
  for (int ht = 0; ht < 4; ++ht) {
    float q[4];
#pragma unroll
    for (int r = 0; r < 4; ++r) {
      q[r] = __builtin_amdgcn_fmed3f(
          rintf(fmaf(acc[ht][r], pb[32 * ht + 2 * r], pb[32 * ht + 2 * r + 1])),
          0.f, 255.f);
    }
    uint8_t* bp = bw + c * PITCH + 32 * ht + 8 * g;   // row c, bytes 2h..2h+7
    *(uint32_t*)(bp)     = packbf(q[0], q[1]);
    *(uint32_t*)(bp + 4) = packbf(q[2], q[3]);
  }
  // same-wave cross-lane exchange: DS ops from one wave are processed in order
#pragma unroll
  for (int kt = 0; kt < 2; ++kt) {
    const uint8_t* rp = bw + c * PITCH + 64 * kt + 16 * g;  // k = 32kt+8g+j
    union { u32x4 u; bf16x8 s; } uv;
    uv.u = *(const u32x4*)rp;
    bfr[kt] = uv.s;
  }
}

__global__ __launch_bounds__(1024, 4) void fused_mfma_kernel(
    const float* __restrict__ x, const uint8_t* __restrict__ wsb,
    float* __restrict__ out)
{
  // LDS: ws image 52.8K + xs 64K + bounce 36.9K = 155.2K -> 1 block/CU, 16 waves.
  __shared__ __align__(16) uint8_t wlds[WS_STAGE];
  __shared__ __align__(16) uint8_t xs[16 * 4096];        // per-wave: 2 bufs x 2KB
  __shared__ __align__(16) uint8_t bnc[16][16 * PITCH];  // per-wave bounce tiles

  const int t = threadIdx.x;
  const int w = t >> 6, l = t & 63, g = (l >> 4) & 3, c = l & 15;
  const size_t rowbase = (size_t)blockIdx.x * 256;

  // Stage ws -> LDS: 4 chunks of 16KB (1024 lanes x 16B), linear both sides.
#pragma unroll
  for (int i = 0; i < 4; ++i) {
    const int off = i * 16384 + t * 16;
    if (off < WS_STAGE) {
      __builtin_amdgcn_global_load_lds(
          (const __attribute__((address_space(1))) void*)(wsb + off),
          (__attribute__((address_space(3))) void*)(wlds + off), 16, 0, 0);
    }
  }

  // x DMA staging: wave w owns rows 16w..16w+15. Chunk ch = k in [32ch,32ch+32):
  // 16 rows x 128B = 2 DMAs x 1KB. DMA i covers rows 8i..8i+7 linearly
  // (lane l -> row 8i + (l>>3), slot l&7); global source slot pre-XOR'd with
  // row&7 so the read-side XOR lands on the right data (r9-verified).
  const float* __restrict__ xwave = x + (rowbase + 16 * w) * IN_;
#define STAGE(ch_, buf_)                                                             \
  {                                                                                  \
    _Pragma("unroll")                                                                \
    for (int i = 0; i < 2; ++i) {                                                    \
      const int row8  = 8 * i + (l >> 3);          /* this lane's dest row */        \
      const int sslot = (l & 7) ^ (row8 & 7);      /* pre-swizzled global slot */    \
      const float* src = xwave + (size_t)row8 * IN_ + (ch_) * 32 + 4 * sslot;        \
      void* dst = (char*)xs + w * 4096 + (buf_) * 2048 + i * 1024;                   \
      __builtin_amdgcn_global_load_lds(                                              \
          (const __attribute__((address_space(1))) void*)src,                        \
          (__attribute__((address_space(3))) void*)dst, 16, 0, 0);                   \
    }                                                                                \
  }

  STAGE(0, 0);
  __syncthreads();   // drains vmcnt: ws image + chunk 0 ready

  const float* pars = (const float*)(wlds + PAR);
  const float So = pars[403];

  f32x4 acc[4];
#pragma unroll
  for (int ht = 0; ht < 4; ++ht) acc[ht] = f32x4{0.f, 0.f, 0.f, 0.f};

  // ---- Layer 1: 8 k-tiles (= 8 chunks), DMA double-buffer, barrier-free ----
#pragma unroll
  for (int s = 0; s < 8; ++s) {
    if (s < 7) STAGE(s + 1, (s + 1) & 1);
    if (s < 7) { asm volatile("s_waitcnt vmcnt(2)" ::: "memory"); }
    else       { asm volatile("s_waitcnt vmcnt(0)" ::: "memory"); }

    // read this wave's row c from buf s&1; global slots 2g, 2g+1 -> XOR c&7
    const uint8_t* xb = xs + w * 4096 + (s & 1) * 2048 + c * 128;
    const f32x4 e0 = *(const f32x4*)(xb + (((2 * g)     ^ (c & 7)) << 4));
    const f32x4 e1 = *(const f32x4*)(xb + (((2 * g + 1) ^ (c & 7)) << 4));

    u32x4 wf[4];
#pragma unroll
    for (int ht = 0; ht < 4; ++ht)
      wf[ht] = *(const u32x4*)(wlds + W1F + (size_t)(((ht * 8 + s) * 64) + l) * 16);

    const float el[8] = {e0.x, e0.y, e0.z, e0.w, e1.x, e1.y, e1.z, e1.w};

    float d[8], e2[8];
#pragma unroll
    for (int q = 0; q < 8; ++q) d[q] = el[q] - truncbf(el[q]);   // exact
#pragma unroll
    for (int q = 0; q < 8; ++q) e2[q] = d[q] - truncbf(d[q]);    // exact

    union { uint32_t u[4]; bf16x8 v; } bh, bl1, bl2;
#pragma unroll
    for (int q = 0; q < 4; ++q) {
      bh.u[q]  = packbf(el[2 * q], el[2 * q + 1]);
      bl1.u[q] = packbf(d[2 * q],  d[2 * q + 1]);
      bl2.u[q] = packbf(e2[2 * q], e2[2 * q + 1]);
    }
#pragma unroll
    for (int ht = 0; ht < 4; ++ht) acc[ht] = MFMA(wf[ht], bh.v,  acc[ht]);
#pragma unroll
    for (int ht = 0; ht < 4; ++ht) acc[ht] = MFMA(wf[ht], bl1.v, acc[ht]);
#pragma unroll
    for (int ht = 0; ht < 4; ++ht) acc[ht] = MFMA(wf[ht], bl2.v, acc[ht]);
  }
#undef STAGE

  uint8_t* bw = &bnc[w][0];
  bf16x8 bfr[2];

  // ---- Layer 2 ----
  epilog(acc, pars, 0, bw, g, c, bfr);
  f32x4 a2[4];
#pragma unroll
  for (int ht = 0; ht < 4; ++ht) a2[ht] = f32x4{0.f, 0.f, 0.f, 0.f};
#pragma unroll
  for (int kt = 0; kt < 2; ++kt) {
#pragma unroll
    for (int ht = 0; ht < 4; ++ht) {
      const u32x4 wf = *(const u32x4*)(wlds + W2F + (size_t)(((ht * 2 + kt) * 64) + l) * 16);
      a2[ht] = MFMA(wf, bfr[kt], a2[ht]);
    }
  }

  // ---- Layer 3 ----
  epilog(a2, pars, 1, bw, g, c, bfr);
  f32x4 a3[4];
#pragma unroll
  for (int ht = 0; ht < 4; ++ht) a3[ht] = f32x4{0.f, 0.f, 0.f, 0.f};
#pragma unroll
  for (int kt = 0; kt < 2; ++kt) {
#pragma unroll
    for (int ht = 0; ht < 4; ++ht) {
      const u32x4 wf = *(const u32x4*)(wlds + W3F + (size_t)(((ht * 2 + kt) * 64) + l) * 16);
      a3[ht] = MFMA(wf, bfr[kt], a3[ht]);
    }
  }

  // ---- Output layer ----
  epilog(a3, pars, 2, bw, g, c, bfr);
  f32x4 ao = f32x4{0.f, 0.f, 0.f, 0.f};
#pragma unroll
  for (int kt = 0; kt < 2; ++kt) {
    const u32x4 wf = *(const u32x4*)(wlds + WOF + (size_t)((kt * 64) + l) * 16);
    ao = MFMA(wf, bfr[kt], ao);
  }

  const float bo0 = pars[384 + 4 * g + 0];
  const float bo1 = pars[384 + 4 * g + 1];
  const float bo2 = pars[384 + 4 * g + 2];
  const float bo3 = pars[384 + 4 * g + 3];
  f32x4 o;
  o.x = fmaf(ao.x, So, bo0);
  o.y = fmaf(ao.y, So, bo1);
  o.z = fmaf(ao.z, So, bo2);
  o.w = fmaf(ao.w, So, bo3);
  if (g < 3)  // out channels 4g..4g+3; only 0..11 exist
    *(f32x4*)(out + (rowbase + 16 * w + c) * C_ + 4 * g) = o;
}

extern "C" void kernel_launch(void* const* d_in, const int* in_sizes, int n_in,
                              void* d_out, int out_size, void* d_ws, size_t ws_size,
                              hipStream_t stream) {
  // 0:x 1:W1 2:g1 3:b1 4:s1 5:W2 6:g2 7:b2 8:s2 9:W3 10:g3 11:b3 12:s3 13:Wo 14:bo
  const float* x  = (const float*)d_in[0];
  const float* W1 = (const float*)d_in[1];
  const float* g1 = (const float*)d_in[2];
  const float* b1 = (const float*)d_in[3];
  const float* s1 = (const float*)d_in[4];
  const float* W2 = (const float*)d_in[5];
  const float* g2 = (const float*)d_in[6];
  const float* b2 = (const float*)d_in[7];
  const float* s2 = (const float*)d_in[8];
  const float* W3 = (const float*)d_in[9];
  const float* g3 = (const float*)d_in[10];
  const float* b3 = (const float*)d_in[11];
  const float* s3 = (const float*)d_in[12];
  const float* Wo = (const float*)d_in[13];
  const float* bo = (const float*)d_in[14];

  uint8_t* ws = (uint8_t*)d_ws;
  float* out = (float*)d_out;

  prep_kernel<<<4, 1024, 0, stream>>>(W1, W2, W3, Wo, g1, b1, s1, g2, b2, s2,
                                      g3, b3, s3, bo, ws);
  fused_mfma_kernel<<<B_ / 256, 1024, 0, stream>>>(x, ws, out);
}

// Round 21
// 40.951 us; speedup vs baseline: 1.8306x; 1.0066x over previous
//
#include <hip/hip_runtime.h>
#include <stdint.h>

// QuantDenseModelLarge on gfx950 — MFMA formulation.
// Round 21 = r20 (41.2 µs) with a 3-DEEP x DMA pipeline (was 2-deep).
// Discriminating experiment: r12/r14/r16/r20 (four independent x-delivery
// structures) all land at 41±1 µs ≈ 3.4 TB/s read — suspected per-CU
// outstanding-line cap (~4-6KB effective in flight at ~900cy HBM latency).
// r20 kept only 2 DMAs (2KB) outstanding per wave at the vmcnt gate; this
// round keeps 4 (4KB) via 3 buffers + vmcnt(4), prefetch distance 2.
// LDS freed by aliasing each wave's bounce tile into its xs slice (dead
// after layer 1; same-wave DS ops are in-order): wlds 52.8K + xs 96K = 148.8K.
// If unchanged at ~41 µs -> per-CU cap confirmed -> roofline.
//
// Exact identities:
//   quant weights = qw * sw, qw int in [-7,7]  -> exact in bf16
//   QuantReLU out = qa * s,  qa int in [0,255] -> exact in bf16
//   layers 2/3/out: D = sum(qa*qw) exact in f32; y = D*(s*sw)
//   layer 1: x == hi + lo1 + lo2 EXACTLY (3 bf16 truncation limbs)
//   rint(max(y,0)) == med3(rint(y), 0, 255) for the clamp (rint monotone)
//
// MFMA layout (hardware-verified via learn_hip m89/m92 ref-checked GEMMs):
//   A (16x32): lane l holds A[m = l&15][k = 8*(l>>4) + j], j=0..7
//   B (32x16): lane l holds B[k = 8*(l>>4) + j][n = l&15]
//   C/D      : lane l, reg r holds D[row = 4*(l>>4) + r][col = l&15]
//
// x LDS swizzle (r20-verified, rule #21): DMA dest linear; global source slot
// pre-XOR'd with row&7; read side applies the same XOR.

typedef __attribute__((ext_vector_type(4))) float  f32x4;
typedef __attribute__((ext_vector_type(8))) short  bf16x8;
typedef __attribute__((ext_vector_type(4))) unsigned int u32x4;

namespace {
constexpr int B_  = 131072;
constexpr int IN_ = 256;
constexpr int H_  = 58;
constexpr int C_  = 12;

// ws byte offsets (also the wlds image offsets after staging)
constexpr int W1F = 0;        // [ht4][kt8][lane64][j8] bf16 = 32768 B
constexpr int W2F = 32768;    // [ht4][kt2][lane64][j8] bf16 =  8192 B
constexpr int W3F = 40960;    //                                8192 B
constexpr int WOF = 49152;    // [kt2][lane64][j8]      bf16 =  2048 B
constexpr int PAR = 51200;    // 3*64 {A',b'} f32 | bo[16] | {unused x3, So}
constexpr int WS_STAGE = 52816;  // PAR + 404*4, multiple of 16
constexpr int PITCH = 144;    // bounce-tile row pitch (bytes): 128 data + 16 pad
constexpr int XSW  = 6144;    // per-wave xs slice: 3 bufs x 2KB (bounce aliased in)
}

__device__ __forceinline__ uint32_t fu(float f) { return __float_as_uint(f); }
__device__ __forceinline__ float    uf(uint32_t u) { return __uint_as_float(u); }
__device__ __forceinline__ float    truncbf(float v) { return uf(fu(v) & 0xffff0000u); }
// pack bf16(a) into low16, bf16(b) into high16 — single v_perm_b32.
__device__ __forceinline__ uint32_t packbf(float a, float b) {
  return __builtin_amdgcn_perm(fu(b), fu(a), 0x07060302u);
}

__device__ __forceinline__ f32x4 MFMA(u32x4 a, bf16x8 b, f32x4 c) {
  union { u32x4 u; bf16x8 s; } ua; ua.u = a;
  return __builtin_amdgcn_mfma_f32_16x16x32_bf16(ua.s, b, c, 0, 0, 0);
}

// ---------------- prep: quantize + fragment-major arrange + param tables ----------------
__global__ void prep_kernel(
    const float* __restrict__ W1, const float* __restrict__ W2,
    const float* __restrict__ W3, const float* __restrict__ Wo,
    const float* __restrict__ g1, const float* __restrict__ b1, const float* __restrict__ s1,
    const float* __restrict__ g2, const float* __restrict__ b2, const float* __restrict__ s2,
    const float* __restrict__ g3, const float* __restrict__ b3, const float* __restrict__ s3,
    const float* __restrict__ bo,
    uint8_t* __restrict__ wsb)
{
  __shared__ float red[1024];
  const int t = threadIdx.x;
  const int blk = blockIdx.x;
  const float* W; int n;
  switch (blk) {
    case 0: W = W1; n = H_ * IN_; break;
    case 1: W = W2; n = H_ * H_;  break;
    case 2: W = W3; n = H_ * H_;  break;
    default: W = Wo; n = C_ * H_; break;
  }
  float m = 0.f;
  for (int i = t; i < n; i += 1024) m = fmaxf(m, fabsf(W[i]));
  red[t] = m;
  __syncthreads();
  for (int s = 512; s > 0; s >>= 1) { if (t < s) red[t] = fmaxf(red[t], red[t + s]); __syncthreads(); }
  const float sw = red[0] / 7.0f;   // per-tensor symmetric, qmax = 7

  float* pp = (float*)(wsb + PAR);

  if (blk == 0) {
    unsigned short* fr = (unsigned short*)(wsb + W1F);
    for (int i = t; i < 16384; i += 1024) {
      const int j = i & 7, ln = (i >> 3) & 63, kt = (i >> 9) & 7, ht = (i >> 12) & 3;
      const int h = (ht << 4) | (ln & 15);
      const int k = (kt << 5) | (((ln >> 4) & 3) << 3) | j;
      float q = 0.f;
      if (h < H_) q = fminf(fmaxf(rintf(W1[h * IN_ + k] / sw), -7.f), 7.f);
      fr[i] = (unsigned short)(fu(q) >> 16);   // small ints exact in bf16
    }
    const float inv = 1.0f / s1[0];
    if (t < 64) {
      pp[2 * t]     = (t < H_) ? sw * g1[t] * inv : 0.f;   // A' = A/s1
      pp[2 * t + 1] = (t < H_) ? b1[t] * inv : 0.f;        // b' = b/s1
    }
  } else if (blk == 1) {
    unsigned short* fr = (unsigned short*)(wsb + W2F);
    for (int i = t; i < 4096; i += 1024) {
      const int j = i & 7, ln = (i >> 3) & 63, kt = (i >> 9) & 1, ht = (i >> 10) & 3;
      const int h = (ht << 4) | (ln & 15);
      const int k = (kt << 5) | (((ln >> 4) & 3) << 3) | j;
      float q = 0.f;
      if (h < H_ && k < H_) q = fminf(fmaxf(rintf(W2[h * H_ + k] / sw), -7.f), 7.f);
      fr[i] = (unsigned short)(fu(q) >> 16);
    }
    const float inv = 1.0f / s2[0];
    if (t < 64) {
      pp[128 + 2 * t]     = (t < H_) ? s1[0] * sw * g2[t] * inv : 0.f;
      pp[128 + 2 * t + 1] = (t < H_) ? b2[t] * inv : 0.f;
    }
  } else if (blk == 2) {
    unsigned short* fr = (unsigned short*)(wsb + W3F);
    for (int i = t; i < 4096; i += 1024) {
      const int j = i & 7, ln = (i >> 3) & 63, kt = (i >> 9) & 1, ht = (i >> 10) & 3;
      const int h = (ht << 4) | (ln & 15);
      const int k = (kt << 5) | (((ln >> 4) & 3) << 3) | j;
      float q = 0.f;
      if (h < H_ && k < H_) q = fminf(fmaxf(rintf(W3[h * H_ + k] / sw), -7.f), 7.f);
      fr[i] = (unsigned short)(fu(q) >> 16);
    }
    const float inv = 1.0f / s3[0];
    if (t < 64) {
      pp[256 + 2 * t]     = (t < H_) ? s2[0] * sw * g3[t] * inv : 0.f;
      pp[256 + 2 * t + 1] = (t < H_) ? b3[t] * inv : 0.f;
    }
  } else {
    unsigned short* fr = (unsigned short*)(wsb + WOF);
    for (int i = t; i < 1024; i += 1024) {
      const int j = i & 7, ln = (i >> 3) & 63, kt = (i >> 9) & 1;
      const int h = ln & 15;
      const int k = (kt << 5) | (((ln >> 4) & 3) << 3) | j;
      float q = 0.f;
      if (h < C_ && k < H_) q = fminf(fmaxf(rintf(Wo[h * H_ + k] / sw), -7.f), 7.f);
      fr[i] = (unsigned short)(fu(q) >> 16);
    }
    if (t < 16) pp[384 + t] = (t < C_) ? bo[t] : 0.f;
    if (t == 0) pp[403] = s3[0] * sw;   // So
  }
}

// ---------------- epilogue: BN+QuantReLU (prescaled) -> bf16 ints -> LDS bounce -> B-frags ----------------
__device__ __forceinline__ void epilog(
    const f32x4 (&acc)[4], const float* pars, int L,
    uint8_t* bw, int g, int c, bf16x8 (&bfr)[2])
{
  const float* pb = pars + L * 128 + 8 * g;   // {A'(h),b'(h)} pairs, h = 16ht+4g+r
#pragma unroll
  for (int ht = 0; ht < 4; ++ht) {
    float q[4];
#pragma unroll
    for (int r = 0; r < 4; ++r) {
      q[r] = __builtin_amdgcn_fmed3f(
          rintf(fmaf(acc[ht][r], pb[32 * ht + 2 * r], pb[32 * ht + 2 * r + 1])),
          0.f, 255.f);
    }
    uint8_t* bp = bw + c * PITCH + 32 * ht + 8 * g;   // row c, bytes 2h..2h+7
    *(uint32_t*)(bp)     = packbf(q[0], q[1]);
    *(uint32_t*)(bp + 4) = packbf(q[2], q[3]);
  }
  // same-wave cross-lane exchange: DS ops from one wave are processed in order
#pragma unroll
  for (int kt = 0; kt < 2; ++kt) {
    const uint8_t* rp = bw + c * PITCH + 64 * kt + 16 * g;  // k = 32kt+8g+j
    union { u32x4 u; bf16x8 s; } uv;
    uv.u = *(const u32x4*)rp;
    bfr[kt] = uv.s;
  }
}

__global__ __launch_bounds__(1024, 4) void fused_mfma_kernel(
    const float* __restrict__ x, const uint8_t* __restrict__ wsb,
    float* __restrict__ out)
{
  // LDS: ws image 52.8K + xs (16 waves x 6KB, bounce aliased in) 96K = 148.8K.
  __shared__ __align__(16) uint8_t wlds[WS_STAGE];
  __shared__ __align__(16) uint8_t xs[16 * XSW];

  const int t = threadIdx.x;
  const int w = t >> 6, l = t & 63, g = (l >> 4) & 3, c = l & 15;
  const size_t rowbase = (size_t)blockIdx.x * 256;

  // Stage ws -> LDS: 4 chunks of 16KB (1024 lanes x 16B), linear both sides.
#pragma unroll
  for (int i = 0; i < 4; ++i) {
    const int off = i * 16384 + t * 16;
    if (off < WS_STAGE) {
      __builtin_amdgcn_global_load_lds(
          (const __attribute__((address_space(1))) void*)(wsb + off),
          (__attribute__((address_space(3))) void*)(wlds + off), 16, 0, 0);
    }
  }

  // x DMA staging (r20-verified): wave w owns rows 16w..16w+15.
  // Chunk ch: 16 rows x 128B = 2 DMAs x 1KB. DMA i covers rows 8i..8i+7
  // linearly (lane l -> row 8i+(l>>3), slot l&7); source slot pre-XOR'd.
  const float* __restrict__ xwave = x + (rowbase + 16 * w) * IN_;
#define STAGE(ch_, buf_)                                                             \
  {                                                                                  \
    _Pragma("unroll")                                                                \
    for (int i = 0; i < 2; ++i) {                                                    \
      const int row8  = 8 * i + (l >> 3);                                            \
      const int sslot = (l & 7) ^ (row8 & 7);                                        \
      const float* src = xwave + (size_t)row8 * IN_ + (ch_) * 32 + 4 * sslot;        \
      void* dst = (char*)xs + w * XSW + (buf_) * 2048 + i * 1024;                    \
      __builtin_amdgcn_global_load_lds(                                              \
          (const __attribute__((address_space(1))) void*)src,                        \
          (__attribute__((address_space(3))) void*)dst, 16, 0, 0);                   \
    }                                                                                \
  }

  STAGE(0, 0);
  STAGE(1, 1);
  __syncthreads();   // drains vmcnt: ws image + chunks 0,1 ready

  const float* pars = (const float*)(wlds + PAR);
  const float So = pars[403];

  f32x4 acc[4];
#pragma unroll
  for (int ht = 0; ht < 4; ++ht) acc[ht] = f32x4{0.f, 0.f, 0.f, 0.f};

  // ---- Layer 1: 8 k-tiles, 3-deep DMA pipeline (prefetch distance 2) ----
#pragma unroll
  for (int s = 0; s < 8; ++s) {
    if (s < 6) {
      STAGE(s + 2, (s + 2) % 3);
      asm volatile("s_waitcnt vmcnt(4)" ::: "memory");  // chunks s+1,s+2 in flight
    } else if (s == 6) {
      asm volatile("s_waitcnt vmcnt(2)" ::: "memory");  // chunk 7 in flight
    } else {
      asm volatile("s_waitcnt vmcnt(0)" ::: "memory");
    }

    // read this wave's row c from buf s%3; global slots 2g, 2g+1 -> XOR c&7
    const uint8_t* xb = xs + w * XSW + (s % 3) * 2048 + c * 128;
    const f32x4 e0 = *(const f32x4*)(xb + (((2 * g)     ^ (c & 7)) << 4));
    const f32x4 e1 = *(const f32x4*)(xb + (((2 * g + 1) ^ (c & 7)) << 4));

    u32x4 wf[4];
#pragma unroll
    for (int ht = 0; ht < 4; ++ht)
      wf[ht] = *(const u32x4*)(wlds + W1F + (size_t)(((ht * 8 + s) * 64) + l) * 16);

    const float el[8] = {e0.x, e0.y, e0.z, e0.w, e1.x, e1.y, e1.z, e1.w};

    float d[8], e2[8];
#pragma unroll
    for (int q = 0; q < 8; ++q) d[q] = el[q] - truncbf(el[q]);   // exact
#pragma unroll
    for (int q = 0; q < 8; ++q) e2[q] = d[q] - truncbf(d[q]);    // exact

    union { uint32_t u[4]; bf16x8 v; } bh, bl1, bl2;
#pragma unroll
    for (int q = 0; q < 4; ++q) {
      bh.u[q]  = packbf(el[2 * q], el[2 * q + 1]);
      bl1.u[q] = packbf(d[2 * q],  d[2 * q + 1]);
      bl2.u[q] = packbf(e2[2 * q], e2[2 * q + 1]);
    }
#pragma unroll
    for (int ht = 0; ht < 4; ++ht) acc[ht] = MFMA(wf[ht], bh.v,  acc[ht]);
#pragma unroll
    for (int ht = 0; ht < 4; ++ht) acc[ht] = MFMA(wf[ht], bl1.v, acc[ht]);
#pragma unroll
    for (int ht = 0; ht < 4; ++ht) acc[ht] = MFMA(wf[ht], bl2.v, acc[ht]);
  }
#undef STAGE

  // Bounce tile aliased into this wave's (now dead) xs slice. All of this
  // wave's DMAs have completed (vmcnt(0) at s=7); same-wave DS ops are
  // processed in order, so epilog writes cannot pass earlier xs reads.
  uint8_t* bw = xs + w * XSW;
  bf16x8 bfr[2];

  // ---- Layer 2 ----
  epilog(acc, pars, 0, bw, g, c, bfr);
  f32x4 a2[4];
#pragma unroll
  for (int ht = 0; ht < 4; ++ht) a2[ht] = f32x4{0.f, 0.f, 0.f, 0.f};
#pragma unroll
  for (int kt = 0; kt < 2; ++kt) {
#pragma unroll
    for (int ht = 0; ht < 4; ++ht) {
      const u32x4 wf = *(const u32x4*)(wlds + W2F + (size_t)(((ht * 2 + kt) * 64) + l) * 16);
      a2[ht] = MFMA(wf, bfr[kt], a2[ht]);
    }
  }

  // ---- Layer 3 ----
  epilog(a2, pars, 1, bw, g, c, bfr);
  f32x4 a3[4];
#pragma unroll
  for (int ht = 0; ht < 4; ++ht) a3[ht] = f32x4{0.f, 0.f, 0.f, 0.f};
#pragma unroll
  for (int kt = 0; kt < 2; ++kt) {
#pragma unroll
    for (int ht = 0; ht < 4; ++ht) {
      const u32x4 wf = *(const u32x4*)(wlds + W3F + (size_t)(((ht * 2 + kt) * 64) + l) * 16);
      a3[ht] = MFMA(wf, bfr[kt], a3[ht]);
    }
  }

  // ---- Output layer ----
  epilog(a3, pars, 2, bw, g, c, bfr);
  f32x4 ao = f32x4{0.f, 0.f, 0.f, 0.f};
#pragma unroll
  for (int kt = 0; kt < 2; ++kt) {
    const u32x4 wf = *(const u32x4*)(wlds + WOF + (size_t)((kt * 64) + l) * 16);
    ao = MFMA(wf, bfr[kt], ao);
  }

  const float bo0 = pars[384 + 4 * g + 0];
  const float bo1 = pars[384 + 4 * g + 1];
  const float bo2 = pars[384 + 4 * g + 2];
  const float bo3 = pars[384 + 4 * g + 3];
  f32x4 o;
  o.x = fmaf(ao.x, So, bo0);
  o.y = fmaf(ao.y, So, bo1);
  o.z = fmaf(ao.z, So, bo2);
  o.w = fmaf(ao.w, So, bo3);
  if (g < 3)  // out channels 4g..4g+3; only 0..11 exist
    *(f32x4*)(out + (rowbase + 16 * w + c) * C_ + 4 * g) = o;
}

extern "C" void kernel_launch(void* const* d_in, const int* in_sizes, int n_in,
                              void* d_out, int out_size, void* d_ws, size_t ws_size,
                              hipStream_t stream) {
  // 0:x 1:W1 2:g1 3:b1 4:s1 5:W2 6:g2 7:b2 8:s2 9:W3 10:g3 11:b3 12:s3 13:Wo 14:bo
  const float* x  = (const float*)d_in[0];
  const float* W1 = (const float*)d_in[1];
  const float* g1 = (const float*)d_in[2];
  const float* b1 = (const float*)d_in[3];
  const float* s1 = (const float*)d_in[4];
  const float* W2 = (const float*)d_in[5];
  const float* g2 = (const float*)d_in[6];
  const float* b2 = (const float*)d_in[7];
  const float* s2 = (const float*)d_in[8];
  const float* W3 = (const float*)d_in[9];
  const float* g3 = (const float*)d_in[10];
  const float* b3 = (const float*)d_in[11];
  const float* s3 = (const float*)d_in[12];
  const float* Wo = (const float*)d_in[13];
  const float* bo = (const float*)d_in[14];

  uint8_t* ws = (uint8_t*)d_ws;
  float* out = (float*)d_out;

  prep_kernel<<<4, 1024, 0, stream>>>(W1, W2, W3, Wo, g1, b1, s1, g2, b2, s2,
                                      g3, b3, s3, bo, ws);
  fused_mfma_kernel<<<B_ / 256, 1024, 0, stream>>>(x, ws, out);
}